// Round 5
// baseline (123.118 us; speedup 1.0000x reference)
//
#include <hip/hip_runtime.h>
#include <hip/hip_bf16.h>

// Problem constants (inputs fp32)
#define NB 16      // batches
#define NC 64      // channels
#define NN 4096    // H*W query length
#define NM 1024    // pooled kv length
#define ND 8       // C/HEADS attention dim
#define NG 32      // C/2 g channels

typedef short short8 __attribute__((ext_vector_type(8)));
typedef float floatx4 __attribute__((ext_vector_type(4)));

#define LOG2E 1.44269504f

__device__ __forceinline__ short f2bfs(float f) {
    union { __hip_bfloat16 h; short s; } u;
    u.h = __float2bfloat16(f);
    return u.s;
}
__device__ __forceinline__ unsigned pack2bf(float a, float b) {   // accurate RNE
    return (unsigned)(unsigned short)f2bfs(a) | ((unsigned)(unsigned short)f2bfs(b) << 16);
}
__device__ __forceinline__ unsigned pk2fast(float a, float b) {   // round-half-up, 3 instrs
    unsigned ua = __float_as_uint(a) + 0x8000u;
    unsigned ub = __float_as_uint(b) + 0x8000u;
    return __builtin_amdgcn_perm(ub, ua, 0x07060302);
}
__device__ __forceinline__ short8 u4s8(uint4 v) {
    union { uint4 u; short8 s; } c; c.u = v; return c.s;
}

// Coherent (IF-point) 16B access as 2x system-scope relaxed 8B atomics.
// Loads bypass the non-coherent per-XCD L2 -> no acquire fence needed;
// stores write through -> visible at IF once vmcnt retires.
__device__ __forceinline__ uint4 ld_coh(const unsigned* base, size_t u4idx) {
    const unsigned long long* p = (const unsigned long long*)base + u4idx * 2;
    unsigned long long lo = __hip_atomic_load(p,     __ATOMIC_RELAXED,
                                              __HIP_MEMORY_SCOPE_SYSTEM);
    unsigned long long hi = __hip_atomic_load(p + 1, __ATOMIC_RELAXED,
                                              __HIP_MEMORY_SCOPE_SYSTEM);
    return make_uint4((unsigned)lo, (unsigned)(lo >> 32),
                      (unsigned)hi, (unsigned)(hi >> 32));
}
__device__ __forceinline__ void st_coh(unsigned* base, size_t u4idx, uint4 v) {
    unsigned long long* p = (unsigned long long*)base + u4idx * 2;
    __hip_atomic_store(p,     (unsigned long long)v.x | ((unsigned long long)v.y << 32),
                       __ATOMIC_RELAXED, __HIP_MEMORY_SCOPE_SYSTEM);
    __hip_atomic_store(p + 1, (unsigned long long)v.z | ((unsigned long long)v.w << 32),
                       __ATOMIC_RELAXED, __HIP_MEMORY_SCOPE_SYSTEM);
}

// ---------------------------------------------------------------------------
// Fused kernel, plain launch. grid = NB*32 = 512 blocks.
// XCD-local mapping: xcd = blk&7, slot = blk>>3, b = xcd*2+(slot>>5), ph=slot&31.
// Block (b, ph):
//   phase 1: proj for kv-tile ph (phi, g2 -> ws via coherent writethrough
//            stores; theta -> tb regs)
//   per-batch software barrier: vmcnt drain + relaxed arrive/spin by t0.
//   phase 2: flash attention for q-tile ph. g2 is staged through LDS
//            (double-buffered, 1 uint4/thread/kg) so the 4 waves share one
//            coherent-load stream instead of each streaming 128 KB from L3.
//
// LDS layout (floats), time-multiplexed, 16096 floats = 62.9 KB static:
//   0     : lx   [64][132] = 8448   phase 1   | ltr [64][140]=8960 (epilogue)
//   8448  : lwpT 512                          |  (ltr tail overlays lwpT)
//   8960  : lwgT [64][33] = 2112              | lphi 4096 (phase 2 overlay)
//   11072 : lwoT [32][65] = 2080              |  (lphi tail ends 13056)
//   13056 :                                   | lg2 [2][256] uint4 = 2048 fl
//   13152 : lgs  [32][36] = 1152   (overlaid by lg2 in phase 2)
//   14304 : lps  [32][8]  = 256    (overlaid)
//   14560 : lwt  [8][64]  = 512    (overlaid)
//   15072 : lth  [128][8] = 1024   (tail overlaid; dead after tb pack)
// ---------------------------------------------------------------------------
#define KG_STEP(CPP0, CPP1, CG_)                                                         \
    {                                                                                    \
        _Pragma("unroll")                                                                \
        for (int qt = 0; qt < 2; ++qt) {                                                 \
            floatx4 s0 = __builtin_amdgcn_mfma_f32_16x16x32_bf16(                        \
                u4s8(CPP0), u4s8(tb[qt]), (floatx4)0.f, 0, 0, 0);                        \
            floatx4 s1 = __builtin_amdgcn_mfma_f32_16x16x32_bf16(                        \
                u4s8(CPP1), u4s8(tb[qt]), (floatx4)0.f, 0, 0, 0);                        \
            float e0[4], e1[4];                                                          \
            _Pragma("unroll")                                                            \
            for (int r = 0; r < 4; ++r) {                                                \
                e0[r] = __builtin_amdgcn_exp2f(s0[r]);                                   \
                e1[r] = __builtin_amdgcn_exp2f(s1[r]);                                   \
            }                                                                            \
            lsum[qt] += ((e0[0] + e0[1]) + (e0[2] + e0[3]))                              \
                      + ((e1[0] + e1[1]) + (e1[2] + e1[3]));                             \
            uint4 pb = make_uint4(pk2fast(e0[0], e0[1]), pk2fast(e0[2], e0[3]),          \
                                  pk2fast(e1[0], e1[1]), pk2fast(e1[2], e1[3]));         \
            _Pragma("unroll")                                                            \
            for (int ct = 0; ct < 4; ++ct)                                               \
                acc[qt][ct] = __builtin_amdgcn_mfma_f32_16x16x32_bf16(                   \
                    u4s8(CG_[ct]), u4s8(pb), acc[qt][ct], 0, 0, 0);                      \
        }                                                                                \
    }

__global__ void init_flags(int* __restrict__ flags)
{
    flags[threadIdx.x] = 0;
}

__global__ __launch_bounds__(256, 2)
void fused_kernel(const float* __restrict__ x,
                  const float* __restrict__ w_theta,
                  const float* __restrict__ w_phi,
                  const float* __restrict__ w_g,
                  const float* __restrict__ w_o,
                  const float* __restrict__ gamma_p,
                  unsigned* __restrict__ phi_ws,
                  unsigned* __restrict__ g2_ws,
                  int* __restrict__ flags,
                  float* __restrict__ out)
{
    __shared__ __align__(16) float smem[16096];
    float* lx   = smem;                    // [64][132]
    float* lwpT = smem + 8448;             // [64][8]
    float* lwgT = smem + 8960;             // [64][33]
    float* lwoT = smem + 11072;            // [32][65]
    float* lgs  = smem + 13152;            // [32][36]
    float* lps  = smem + 14304;            // [32][8]
    float* lwt  = smem + 14560;            // [8][64]
    float* lth  = smem + 15072;            // [128][8]
    uint4* lphi = (uint4*)(smem + 8960);   // phase 2, overlays lwgT/lwoT
    uint4* lg2  = (uint4*)(smem + 13056);  // phase 2, [2][256] uint4 dbuf
    float* ltr  = smem;                    // epilogue, overlays lx/lwpT

    const int blk  = blockIdx.x;
    const int xcd  = blk & 7;
    const int slot = blk >> 3;
    const int b    = xcd * 2 + (slot >> 5);   // batch: XCD-local
    const int ph   = slot & 31;               // kv-tile (ph1) == q-tile (ph2)
    const int t    = threadIdx.x;
    const int w    = t >> 6;
    const int lane = t & 63;
    const int lm   = lane & 15;
    const int quad = lane >> 4;

    // ================= phase 1: projections =================
    for (int i = t; i < 512; i += 256) {
        lwpT[(i & 63) * 8 + (i >> 6)] = w_phi[i];    // [oc][c] -> [c][oc]
        lwt[i] = w_theta[i];
    }
    for (int i = t; i < 2048; i += 256) {
        lwgT[(i & 63) * 33 + (i >> 6)] = w_g[i];     // [oc][c] -> [c][oc]
        lwoT[(i & 31) * 65 + (i >> 5)] = w_o[i];     // [co][c] -> [c][co]
    }
    const float* xb = x + (size_t)b * NC * NN + (size_t)ph * 128;
    for (int idx = t; idx < 2048; idx += 256) {
        int c = idx >> 5, i4 = idx & 31;
        ((float4*)(lx + c * 132))[i4] = ((const float4*)(xb + (size_t)c * NN))[i4];
    }
    __syncthreads();

    // residual x for the epilogue -> registers (lx gets recycled by ltr)
    float4 xr0[4], xr1[4];
    {
        const int l16 = t & 15;
        #pragma unroll
        for (int io = 0; io < 4; ++io) {
            int co = io * 16 + (t >> 4);
            const float* p = &lx[co * 132 + l16 * 8];
            xr0[io] = ((const float4*)p)[0];
            xr1[io] = ((const float4*)p)[1];
        }
    }

    // ---- g conv + pool: oc = t>>3, position group grp = t&7
    {
        int oc = t >> 3, grp = t & 7;
        float s0[16];
        #pragma unroll
        for (int i = 0; i < 16; ++i) s0[i] = 0.f;
        const float4* xl4 = (const float4*)lx;
        #pragma unroll 4
        for (int c = 0; c < 64; ++c) {
            float4 a0 = xl4[c * 33 + 2 * grp];
            float4 a1 = xl4[c * 33 + 2 * grp + 1];
            float4 b0 = xl4[c * 33 + 16 + 2 * grp];
            float4 b1 = xl4[c * 33 + 17 + 2 * grp];
            float w0 = lwgT[c * 33 + oc];            // 8-way broadcast
            s0[0] = fmaf(w0, a0.x, s0[0]);  s0[1] = fmaf(w0, a0.y, s0[1]);
            s0[2] = fmaf(w0, a0.z, s0[2]);  s0[3] = fmaf(w0, a0.w, s0[3]);
            s0[4] = fmaf(w0, a1.x, s0[4]);  s0[5] = fmaf(w0, a1.y, s0[5]);
            s0[6] = fmaf(w0, a1.z, s0[6]);  s0[7] = fmaf(w0, a1.w, s0[7]);
            s0[8] = fmaf(w0, b0.x, s0[8]);  s0[9] = fmaf(w0, b0.y, s0[9]);
            s0[10] = fmaf(w0, b0.z, s0[10]); s0[11] = fmaf(w0, b0.w, s0[11]);
            s0[12] = fmaf(w0, b1.x, s0[12]); s0[13] = fmaf(w0, b1.y, s0[13]);
            s0[14] = fmaf(w0, b1.z, s0[14]); s0[15] = fmaf(w0, b1.w, s0[15]);
        }
        #pragma unroll
        for (int p = 0; p < 4; ++p)
            lgs[oc * 36 + grp * 4 + p] =
                fmaxf(fmaxf(s0[2 * p], s0[2 * p + 1]), fmaxf(s0[8 + 2 * p], s0[9 + 2 * p]));
    }

    // ---- phi conv + pool: m = t>>3, oc = t&7
    {
        int m = t >> 3, oc = t & 7;
        float s0 = 0.f, s1 = 0.f, s2 = 0.f, s3 = 0.f;
        #pragma unroll 4
        for (int c = 0; c < 64; ++c) {
            float wv = lwpT[c * 8 + oc];             // 8-way broadcast
            const float* xr = &lx[c * 132];
            s0 = fmaf(wv, xr[2 * m],      s0);
            s1 = fmaf(wv, xr[2 * m + 1],  s1);
            s2 = fmaf(wv, xr[64 + 2 * m], s2);
            s3 = fmaf(wv, xr[65 + 2 * m], s3);
        }
        lps[m * 8 + oc] = fmaxf(fmaxf(s0, s1), fmaxf(s2, s3));
    }

    // ---- theta conv (block-local: q-tile == this x-tile)
    {
        int qi = t & 127, och = (t >> 7) * 4;
        float th4[4] = {0.f, 0.f, 0.f, 0.f};
        for (int c = 0; c < 64; ++c) {
            float xv = lx[c * 132 + qi];             // conflict-free
            #pragma unroll
            for (int o = 0; o < 4; ++o)
                th4[o] = fmaf(lwt[(och + o) * 64 + c], xv, th4[o]);  // broadcast
        }
        *(float4*)&lth[qi * 8 + och] = make_float4(th4[0], th4[1], th4[2], th4[3]);
    }
    __syncthreads();

    // ---- g2 = w_o @ g, written in PV A-frag order (coherent writethrough)
    {
        int co = t >> 2, sel = t & 3;      // sel = quad
        int m0a = 4 * sel, m0b = 16 + 4 * sel;
        float v[8];
        #pragma unroll
        for (int mm = 0; mm < 8; ++mm) v[mm] = 0.f;
        #pragma unroll 4
        for (int c = 0; c < 32; ++c) {
            float wv = lwoT[c * 65 + co];
            float4 ga = *(const float4*)&lgs[c * 36 + m0a];
            float4 gb = *(const float4*)&lgs[c * 36 + m0b];
            v[0] = fmaf(wv, ga.x, v[0]); v[1] = fmaf(wv, ga.y, v[1]);
            v[2] = fmaf(wv, ga.z, v[2]); v[3] = fmaf(wv, ga.w, v[3]);
            v[4] = fmaf(wv, gb.x, v[4]); v[5] = fmaf(wv, gb.y, v[5]);
            v[6] = fmaf(wv, gb.z, v[6]); v[7] = fmaf(wv, gb.w, v[7]);
        }
        uint4 pk;
        pk.x = pack2bf(v[0], v[1]); pk.y = pack2bf(v[2], v[3]);   // kt0
        pk.z = pack2bf(v[4], v[5]); pk.w = pack2bf(v[6], v[7]);   // kt1
        int ln = (sel << 4) | (co & 15);
        st_coh(g2_ws, (((size_t)b * 4 + (co >> 4)) * 32 + ph) * 64 + ln, pk);
    }

    // ---- phi pack (coherent writethrough)
    if (t < 32) {
        const float* pr = &lps[t * 8];
        uint4 pk;
        pk.x = pack2bf(pr[0], pr[1]); pk.y = pack2bf(pr[2], pr[3]);
        pk.z = pack2bf(pr[4], pr[5]); pk.w = pack2bf(pr[6], pr[7]);
        st_coh(phi_ws, (size_t)b * NM + ph * 32 + t, pk);
    }

    // ---- theta B-frags into registers (survive the barrier)
    uint4 tb[2];
    #pragma unroll
    for (int qt = 0; qt < 2; ++qt) {
        const float* thp = &lth[(w * 32 + qt * 16 + lm) * 8];
        float4 a = ((const float4*)thp)[0], c4 = ((const float4*)thp)[1];
        uint4 v;
        v.x = pack2bf(a.x * LOG2E, a.y * LOG2E);
        v.y = pack2bf(a.z * LOG2E, a.w * LOG2E);
        v.z = pack2bf(c4.x * LOG2E, c4.y * LOG2E);
        v.w = pack2bf(c4.z * LOG2E, c4.w * LOG2E);
        tb[qt].x = quad == 0 ? v.x : 0u;
        tb[qt].y = quad == 0 ? v.y : 0u;
        tb[qt].z = quad == 0 ? v.z : 0u;
        tb[qt].w = quad == 0 ? v.w : 0u;
    }

    // ======== per-batch software barrier (32 producer blocks of batch b) ====
    asm volatile("s_waitcnt vmcnt(0)" ::: "memory");
    __syncthreads();
    if (t == 0) {
        __hip_atomic_fetch_add(&flags[b * 32], 1, __ATOMIC_RELAXED,
                               __HIP_MEMORY_SCOPE_AGENT);
        while (__hip_atomic_load(&flags[b * 32], __ATOMIC_RELAXED,
                                 __HIP_MEMORY_SCOPE_AGENT) < 32)
            __builtin_amdgcn_s_sleep(8);
    }
    __syncthreads();

    // ================= phase 2: attention =================
    // g2 LDS staging: thread t covers ct = t>>6 (its wave), lane = t&63.
    const size_t gbase = ((size_t)b * 4 + w) * 32 * 64 + lane;  // + kg*64
    lg2[t] = ld_coh(g2_ws, gbase);                 // stage kg = 0 into buf 0
    for (int kk = t; kk < NM; kk += 256)
        lphi[kk] = ld_coh(phi_ws, (size_t)b * NM + kk);
    __syncthreads();                               // phi + g2 buf0 ready

    floatx4 acc[2][4];
    #pragma unroll
    for (int qt = 0; qt < 2; ++qt)
        #pragma unroll
        for (int ct = 0; ct < 4; ++ct) acc[qt][ct] = (floatx4)0.f;
    float lsum[2] = {0.f, 0.f};

    for (int kg = 0; kg < 32; ++kg) {
        // stage kg+1 into buf^1 (the buffer everyone finished reading at the
        // last barrier); full-iteration double-buffer slack hides IF latency
        if (kg < 31)
            lg2[((kg + 1) & 1) * 256 + t] = ld_coh(g2_ws, gbase + (kg + 1) * 64);

        uint4 c0 = lphi[kg * 32 + lm];
        uint4 c1 = lphi[kg * 32 + 16 + lm];
        uint4 cg[4];
        #pragma unroll
        for (int ct = 0; ct < 4; ++ct)
            cg[ct] = lg2[(kg & 1) * 256 + ct * 64 + lane];   // conflict-free b128

        KG_STEP(c0, c1, cg);

        __syncthreads();   // drains this iter's reads of buf + stage writes
    }

    // softmax denominators: quads partition the 32 keys/kg at q=lm
    float inv[2];
    {
        float l0 = lsum[0]; l0 += __shfl_xor(l0, 16); l0 += __shfl_xor(l0, 32);
        float l1 = lsum[1]; l1 += __shfl_xor(l1, 16); l1 += __shfl_xor(l1, 32);
        inv[0] = 1.0f / l0; inv[1] = 1.0f / l1;
    }

    const float gamma = gamma_p[0];

    // transpose epilogue: normalized acc -> ltr[co][q'], then coalesced stores
    #pragma unroll
    for (int qt = 0; qt < 2; ++qt)
        #pragma unroll
        for (int ct = 0; ct < 4; ++ct)
            #pragma unroll
            for (int r = 0; r < 4; ++r)
                ltr[(ct * 16 + quad * 4 + r) * 140 + w * 32 + qt * 16 + lm]
                    = acc[qt][ct][r] * inv[qt];
    __syncthreads();

    // 16-lane group covers one co row of 128 q; residual x from registers
    {
        const int l16 = t & 15;
        #pragma unroll
        for (int io = 0; io < 4; ++io) {
            int co = io * 16 + (t >> 4);
            size_t base = ((size_t)b * NC + co) * NN + (size_t)ph * 128 + l16 * 8;
            const float* tr = &ltr[co * 140 + l16 * 8];
            float4 t0 = ((const float4*)tr)[0];
            float4 t1 = ((const float4*)tr)[1];
            float4 o0 = make_float4(fmaf(gamma, t0.x, xr0[io].x), fmaf(gamma, t0.y, xr0[io].y),
                                    fmaf(gamma, t0.z, xr0[io].z), fmaf(gamma, t0.w, xr0[io].w));
            float4 o1 = make_float4(fmaf(gamma, t1.x, xr1[io].x), fmaf(gamma, t1.y, xr1[io].y),
                                    fmaf(gamma, t1.z, xr1[io].z), fmaf(gamma, t1.w, xr1[io].w));
            *(float4*)(out + base)     = o0;
            *(float4*)(out + base + 4) = o1;
        }
    }
}

// ---------------------------------------------------------------------------
extern "C" void kernel_launch(void* const* d_in, const int* in_sizes, int n_in,
                              void* d_out, int out_size, void* d_ws, size_t ws_size,
                              hipStream_t stream)
{
    const float* x  = (const float*)d_in[0];
    const float* wt = (const float*)d_in[1];
    const float* wp = (const float*)d_in[2];
    const float* wg = (const float*)d_in[3];
    const float* wo = (const float*)d_in[4];
    const float* gm = (const float*)d_in[5];
    float* out = (float*)d_out;

    // ws (bf16, packed): phi 256 KB | g2 (frag order) 2 MB | barrier flags
    unsigned* phi_ws = (unsigned*)d_ws;
    unsigned* g2_ws  = phi_ws + (size_t)NB * NM * ND / 2;
    int* flags = (int*)((char*)d_ws + (size_t)(256 * 1024 + 2 * 1024 * 1024));

    init_flags<<<1, NB * 32, 0, stream>>>(flags);
    fused_kernel<<<NB * 32, 256, 0, stream>>>(x, wt, wp, wg, wo, gm,
                                              phi_ws, g2_ws, flags, out);
}

// Round 6
// 116.914 us; speedup vs baseline: 1.0531x; 1.0531x over previous
//
#include <hip/hip_runtime.h>
#include <hip/hip_bf16.h>

// Problem constants (inputs fp32)
#define NB 16      // batches
#define NC 64      // channels
#define NN 4096    // H*W query length
#define NM 1024    // pooled kv length
#define ND 8       // C/HEADS attention dim
#define NG 32      // C/2 g channels

typedef short short8 __attribute__((ext_vector_type(8)));
typedef float floatx4 __attribute__((ext_vector_type(4)));

#define LOG2E 1.44269504f

__device__ __forceinline__ short f2bfs(float f) {
    union { __hip_bfloat16 h; short s; } u;
    u.h = __float2bfloat16(f);
    return u.s;
}
__device__ __forceinline__ unsigned pack2bf(float a, float b) {   // accurate RNE
    return (unsigned)(unsigned short)f2bfs(a) | ((unsigned)(unsigned short)f2bfs(b) << 16);
}
__device__ __forceinline__ unsigned pk2fast(float a, float b) {   // round-half-up, 3 instrs
    unsigned ua = __float_as_uint(a) + 0x8000u;
    unsigned ub = __float_as_uint(b) + 0x8000u;
    return __builtin_amdgcn_perm(ub, ua, 0x07060302);
}
__device__ __forceinline__ short8 u4s8(uint4 v) {
    union { uint4 u; short8 s; } c; c.u = v; return c.s;
}

// Coherent (IF-point) 16B access as 2x system-scope relaxed 8B atomics.
// Loads bypass the non-coherent per-XCD L2 -> no acquire fence needed;
// stores write through -> visible at IF once vmcnt retires.
__device__ __forceinline__ uint4 ld_coh(const unsigned* base, size_t u4idx) {
    const unsigned long long* p = (const unsigned long long*)base + u4idx * 2;
    unsigned long long lo = __hip_atomic_load(p,     __ATOMIC_RELAXED,
                                              __HIP_MEMORY_SCOPE_SYSTEM);
    unsigned long long hi = __hip_atomic_load(p + 1, __ATOMIC_RELAXED,
                                              __HIP_MEMORY_SCOPE_SYSTEM);
    return make_uint4((unsigned)lo, (unsigned)(lo >> 32),
                      (unsigned)hi, (unsigned)(hi >> 32));
}
__device__ __forceinline__ void st_coh(unsigned* base, size_t u4idx, uint4 v) {
    unsigned long long* p = (unsigned long long*)base + u4idx * 2;
    __hip_atomic_store(p,     (unsigned long long)v.x | ((unsigned long long)v.y << 32),
                       __ATOMIC_RELAXED, __HIP_MEMORY_SCOPE_SYSTEM);
    __hip_atomic_store(p + 1, (unsigned long long)v.z | ((unsigned long long)v.w << 32),
                       __ATOMIC_RELAXED, __HIP_MEMORY_SCOPE_SYSTEM);
}

// ---------------------------------------------------------------------------
// Fused kernel, plain launch. grid = NB*32 = 512 blocks.
// XCD-local mapping: xcd = blk&7, slot = blk>>3, b = xcd*2+(slot>>5), ph=slot&31.
// Block (b, ph):
//   phase 1: proj for kv-tile ph. g-conv restructured: 2 oc x half-c per
//            thread (halves ds_read_b128 count), combine via __shfl_xor(.,1);
//            phi-conv reads float2 pairs (halves its LDS instr count).
//   per-batch software barrier: vmcnt drain + relaxed arrive/spin by t0.
//   phase 2: flash attention. g2 staged via 2-pair-deep REGISTER pipeline
//            (T14 issue-early/write-late) into a pair-granular LDS dbuf ->
//            ~1400 cyc slack vs ~800 cyc IF latency, 16 barriers not 32.
//
// LDS (floats), 16096 = 62.9 KB static, time-multiplexed:
//  phase 1: lx[64][132]=8448 | lwpT 512 | lwgT[64][33] | lwoT[32][65]
//           | lgs[32][36] | lps[32][8] | lwt 512 | lth[128][8]
//  phase 2: lphi 1024 uint4 @0 | lg2 [2 buf][2 kg][256] uint4 @4096
//  epilogue: ltr[64][140] @0
// ---------------------------------------------------------------------------
#define KG_STEP(CPP0, CPP1, CG_)                                                         \
    {                                                                                    \
        _Pragma("unroll")                                                                \
        for (int qt = 0; qt < 2; ++qt) {                                                 \
            floatx4 s0 = __builtin_amdgcn_mfma_f32_16x16x32_bf16(                        \
                u4s8(CPP0), u4s8(tb[qt]), (floatx4)0.f, 0, 0, 0);                        \
            floatx4 s1 = __builtin_amdgcn_mfma_f32_16x16x32_bf16(                        \
                u4s8(CPP1), u4s8(tb[qt]), (floatx4)0.f, 0, 0, 0);                        \
            float e0[4], e1[4];                                                          \
            _Pragma("unroll")                                                            \
            for (int r = 0; r < 4; ++r) {                                                \
                e0[r] = __builtin_amdgcn_exp2f(s0[r]);                                   \
                e1[r] = __builtin_amdgcn_exp2f(s1[r]);                                   \
            }                                                                            \
            lsum[qt] += ((e0[0] + e0[1]) + (e0[2] + e0[3]))                              \
                      + ((e1[0] + e1[1]) + (e1[2] + e1[3]));                             \
            uint4 pb = make_uint4(pk2fast(e0[0], e0[1]), pk2fast(e0[2], e0[3]),          \
                                  pk2fast(e1[0], e1[1]), pk2fast(e1[2], e1[3]));         \
            _Pragma("unroll")                                                            \
            for (int ct = 0; ct < 4; ++ct)                                               \
                acc[qt][ct] = __builtin_amdgcn_mfma_f32_16x16x32_bf16(                   \
                    u4s8(CG_[ct]), u4s8(pb), acc[qt][ct], 0, 0, 0);                      \
        }                                                                                \
    }

__global__ void init_flags(int* __restrict__ flags)
{
    flags[threadIdx.x] = 0;
}

__global__ __launch_bounds__(256, 2)
void fused_kernel(const float* __restrict__ x,
                  const float* __restrict__ w_theta,
                  const float* __restrict__ w_phi,
                  const float* __restrict__ w_g,
                  const float* __restrict__ w_o,
                  const float* __restrict__ gamma_p,
                  unsigned* __restrict__ phi_ws,
                  unsigned* __restrict__ g2_ws,
                  int* __restrict__ flags,
                  float* __restrict__ out)
{
    __shared__ __align__(16) float smem[16096];
    float* lx   = smem;                    // [64][132]
    float* lwpT = smem + 8448;             // [64][8]
    float* lwgT = smem + 8960;             // [64][33]
    float* lwoT = smem + 11072;            // [32][65]
    float* lgs  = smem + 13152;            // [32][36]
    float* lps  = smem + 14304;            // [32][8]
    float* lwt  = smem + 14560;            // [8][64]
    float* lth  = smem + 15072;            // [128][8]
    uint4* lphi = (uint4*)smem;            // phase 2: [1024], overlays lx
    uint4* lg2  = (uint4*)(smem + 4096);   // phase 2: [2][2][256] uint4
    float* ltr  = smem;                    // epilogue: [64][140]

    const int blk  = blockIdx.x;
    const int xcd  = blk & 7;
    const int slot = blk >> 3;
    const int b    = xcd * 2 + (slot >> 5);   // batch: XCD-local
    const int ph   = slot & 31;               // kv-tile (ph1) == q-tile (ph2)
    const int t    = threadIdx.x;
    const int w    = t >> 6;
    const int lane = t & 63;
    const int lm   = lane & 15;
    const int quad = lane >> 4;

    // ================= phase 1: projections =================
    for (int i = t; i < 512; i += 256) {
        lwpT[(i & 63) * 8 + (i >> 6)] = w_phi[i];    // [oc][c] -> [c][oc]
        lwt[i] = w_theta[i];
    }
    for (int i = t; i < 2048; i += 256) {
        lwgT[(i & 63) * 33 + (i >> 6)] = w_g[i];     // [oc][c] -> [c][oc]
        lwoT[(i & 31) * 65 + (i >> 5)] = w_o[i];     // [co][c] -> [c][co]
    }
    const float* xb = x + (size_t)b * NC * NN + (size_t)ph * 128;
    for (int idx = t; idx < 2048; idx += 256) {
        int c = idx >> 5, i4 = idx & 31;
        ((float4*)(lx + c * 132))[i4] = ((const float4*)(xb + (size_t)c * NN))[i4];
    }
    __syncthreads();

    // residual x for the epilogue -> registers (lx gets recycled)
    float4 xr0[4], xr1[4];
    {
        const int l16 = t & 15;
        #pragma unroll
        for (int io = 0; io < 4; ++io) {
            int co = io * 16 + (t >> 4);
            const float* p = &lx[co * 132 + l16 * 8];
            xr0[io] = ((const float4*)p)[0];
            xr1[io] = ((const float4*)p)[1];
        }
    }

    // ---- g conv + pool: 2 oc x half-c per thread, in-wave combine.
    //      h = t&1 (c-half), grp = (t>>1)&7 (8-pos group), ocp = t>>4 (0..15)
    {
        int h = t & 1, grp = (t >> 1) & 7, ocp = t >> 4;
        float s0[32];
        #pragma unroll
        for (int i = 0; i < 32; ++i) s0[i] = 0.f;
        const float4* xl4 = (const float4*)lx;
        const int cbase = h * 32;
        #pragma unroll 4
        for (int cc = 0; cc < 32; ++cc) {
            int c = cbase + cc;
            float4 a0 = xl4[c * 33 + 2 * grp];
            float4 a1 = xl4[c * 33 + 2 * grp + 1];
            float4 b0 = xl4[c * 33 + 16 + 2 * grp];
            float4 b1 = xl4[c * 33 + 17 + 2 * grp];
            float w0 = lwgT[c * 33 + ocp];
            float w1 = lwgT[c * 33 + ocp + 16];
            s0[0]  = fmaf(w0, a0.x, s0[0]);  s0[1]  = fmaf(w0, a0.y, s0[1]);
            s0[2]  = fmaf(w0, a0.z, s0[2]);  s0[3]  = fmaf(w0, a0.w, s0[3]);
            s0[4]  = fmaf(w0, a1.x, s0[4]);  s0[5]  = fmaf(w0, a1.y, s0[5]);
            s0[6]  = fmaf(w0, a1.z, s0[6]);  s0[7]  = fmaf(w0, a1.w, s0[7]);
            s0[8]  = fmaf(w0, b0.x, s0[8]);  s0[9]  = fmaf(w0, b0.y, s0[9]);
            s0[10] = fmaf(w0, b0.z, s0[10]); s0[11] = fmaf(w0, b0.w, s0[11]);
            s0[12] = fmaf(w0, b1.x, s0[12]); s0[13] = fmaf(w0, b1.y, s0[13]);
            s0[14] = fmaf(w0, b1.z, s0[14]); s0[15] = fmaf(w0, b1.w, s0[15]);
            s0[16] = fmaf(w1, a0.x, s0[16]); s0[17] = fmaf(w1, a0.y, s0[17]);
            s0[18] = fmaf(w1, a0.z, s0[18]); s0[19] = fmaf(w1, a0.w, s0[19]);
            s0[20] = fmaf(w1, a1.x, s0[20]); s0[21] = fmaf(w1, a1.y, s0[21]);
            s0[22] = fmaf(w1, a1.z, s0[22]); s0[23] = fmaf(w1, a1.w, s0[23]);
            s0[24] = fmaf(w1, b0.x, s0[24]); s0[25] = fmaf(w1, b0.y, s0[25]);
            s0[26] = fmaf(w1, b0.z, s0[26]); s0[27] = fmaf(w1, b0.w, s0[27]);
            s0[28] = fmaf(w1, b1.x, s0[28]); s0[29] = fmaf(w1, b1.y, s0[29]);
            s0[30] = fmaf(w1, b1.z, s0[30]); s0[31] = fmaf(w1, b1.w, s0[31]);
        }
        // combine c-halves across lane pairs (xor 1 -> DPP, cheap)
        #pragma unroll
        for (int i = 0; i < 32; ++i) s0[i] += __shfl_xor(s0[i], 1);
        // lane h=0 writes oc=ocp, h=1 writes oc=ocp+16 (branchless, static idx)
        int oc = ocp + h * 16;
        #pragma unroll
        for (int p = 0; p < 4; ++p) {
            float va = fmaxf(fmaxf(s0[2 * p], s0[2 * p + 1]),
                             fmaxf(s0[8 + 2 * p], s0[9 + 2 * p]));
            float vb = fmaxf(fmaxf(s0[16 + 2 * p], s0[17 + 2 * p]),
                             fmaxf(s0[24 + 2 * p], s0[25 + 2 * p]));
            lgs[oc * 36 + grp * 4 + p] = h ? vb : va;
        }
    }

    // ---- phi conv + pool: m = t>>3, oc = t&7 (float2 pair reads)
    {
        int m = t >> 3, oc = t & 7;
        float s0 = 0.f, s1 = 0.f, s2 = 0.f, s3 = 0.f;
        #pragma unroll 4
        for (int c = 0; c < 64; ++c) {
            float wv = lwpT[c * 8 + oc];             // 8-way broadcast
            const float* xr = &lx[c * 132];
            float2 q0 = *(const float2*)(xr + 2 * m);
            float2 q1 = *(const float2*)(xr + 64 + 2 * m);
            s0 = fmaf(wv, q0.x, s0);
            s1 = fmaf(wv, q0.y, s1);
            s2 = fmaf(wv, q1.x, s2);
            s3 = fmaf(wv, q1.y, s3);
        }
        lps[m * 8 + oc] = fmaxf(fmaxf(s0, s1), fmaxf(s2, s3));
    }

    // ---- theta conv (block-local: q-tile == this x-tile)
    {
        int qi = t & 127, och = (t >> 7) * 4;
        float th4[4] = {0.f, 0.f, 0.f, 0.f};
        for (int c = 0; c < 64; ++c) {
            float xv = lx[c * 132 + qi];             // conflict-free
            #pragma unroll
            for (int o = 0; o < 4; ++o)
                th4[o] = fmaf(lwt[(och + o) * 64 + c], xv, th4[o]);  // broadcast
        }
        *(float4*)&lth[qi * 8 + och] = make_float4(th4[0], th4[1], th4[2], th4[3]);
    }
    __syncthreads();

    // ---- g2 = w_o @ g, written in PV A-frag order (coherent writethrough)
    {
        int co = t >> 2, sel = t & 3;      // sel = quad
        int m0a = 4 * sel, m0b = 16 + 4 * sel;
        float v[8];
        #pragma unroll
        for (int mm = 0; mm < 8; ++mm) v[mm] = 0.f;
        #pragma unroll 4
        for (int c = 0; c < 32; ++c) {
            float wv = lwoT[c * 65 + co];
            float4 ga = *(const float4*)&lgs[c * 36 + m0a];
            float4 gb = *(const float4*)&lgs[c * 36 + m0b];
            v[0] = fmaf(wv, ga.x, v[0]); v[1] = fmaf(wv, ga.y, v[1]);
            v[2] = fmaf(wv, ga.z, v[2]); v[3] = fmaf(wv, ga.w, v[3]);
            v[4] = fmaf(wv, gb.x, v[4]); v[5] = fmaf(wv, gb.y, v[5]);
            v[6] = fmaf(wv, gb.z, v[6]); v[7] = fmaf(wv, gb.w, v[7]);
        }
        uint4 pk;
        pk.x = pack2bf(v[0], v[1]); pk.y = pack2bf(v[2], v[3]);   // kt0
        pk.z = pack2bf(v[4], v[5]); pk.w = pack2bf(v[6], v[7]);   // kt1
        int ln = (sel << 4) | (co & 15);
        st_coh(g2_ws, (((size_t)b * 4 + (co >> 4)) * 32 + ph) * 64 + ln, pk);
    }

    // ---- phi pack (coherent writethrough)
    if (t < 32) {
        const float* pr = &lps[t * 8];
        uint4 pk;
        pk.x = pack2bf(pr[0], pr[1]); pk.y = pack2bf(pr[2], pr[3]);
        pk.z = pack2bf(pr[4], pr[5]); pk.w = pack2bf(pr[6], pr[7]);
        st_coh(phi_ws, (size_t)b * NM + ph * 32 + t, pk);
    }

    // ---- theta B-frags into registers (survive the barrier)
    uint4 tb[2];
    #pragma unroll
    for (int qt = 0; qt < 2; ++qt) {
        const float* thp = &lth[(w * 32 + qt * 16 + lm) * 8];
        float4 a = ((const float4*)thp)[0], c4 = ((const float4*)thp)[1];
        uint4 v;
        v.x = pack2bf(a.x * LOG2E, a.y * LOG2E);
        v.y = pack2bf(a.z * LOG2E, a.w * LOG2E);
        v.z = pack2bf(c4.x * LOG2E, c4.y * LOG2E);
        v.w = pack2bf(c4.z * LOG2E, c4.w * LOG2E);
        tb[qt].x = quad == 0 ? v.x : 0u;
        tb[qt].y = quad == 0 ? v.y : 0u;
        tb[qt].z = quad == 0 ? v.z : 0u;
        tb[qt].w = quad == 0 ? v.w : 0u;
    }

    // ======== per-batch software barrier (32 producer blocks of batch b) ====
    asm volatile("s_waitcnt vmcnt(0)" ::: "memory");
    __syncthreads();
    if (t == 0) {
        __hip_atomic_fetch_add(&flags[b * 32], 1, __ATOMIC_RELAXED,
                               __HIP_MEMORY_SCOPE_AGENT);
        while (__hip_atomic_load(&flags[b * 32], __ATOMIC_RELAXED,
                                 __HIP_MEMORY_SCOPE_AGENT) < 32)
            __builtin_amdgcn_s_sleep(8);
    }
    __syncthreads();

    // ================= phase 2: attention =================
    // g2 register pipeline: thread t serves ct = w, lane slot; 2 kg-pairs deep.
    const size_t gbase = ((size_t)b * 4 + w) * 32 * 64 + lane;

    lg2[0 * 512 + 0 * 256 + t] = ld_coh(g2_ws, gbase + 0 * 64);   // pair 0
    lg2[0 * 512 + 1 * 256 + t] = ld_coh(g2_ws, gbase + 1 * 64);
    uint4 pA0 = ld_coh(g2_ws, gbase + 2 * 64);                    // pair 1
    uint4 pA1 = ld_coh(g2_ws, gbase + 3 * 64);
    uint4 pB0 = ld_coh(g2_ws, gbase + 4 * 64);                    // pair 2
    uint4 pB1 = ld_coh(g2_ws, gbase + 5 * 64);
    for (int kk = t; kk < NM; kk += 256)
        lphi[kk] = ld_coh(phi_ws, (size_t)b * NM + kk);
    __syncthreads();                               // phi + g2 pair0 ready

    floatx4 acc[2][4];
    #pragma unroll
    for (int qt = 0; qt < 2; ++qt)
        #pragma unroll
        for (int ct = 0; ct < 4; ++ct) acc[qt][ct] = (floatx4)0.f;
    float lsum[2] = {0.f, 0.f};

    for (int kgp = 0; kgp < 16; ++kgp) {
        const int buf = (kgp & 1) * 512;
        if (kgp < 15) {
            const int nbuf = ((kgp & 1) ^ 1) * 512;
            lg2[nbuf + t]       = pA0;             // pair kgp+1, loaded 2 iters ago
            lg2[nbuf + 256 + t] = pA1;
            pA0 = pB0; pA1 = pB1;
            if (kgp < 13) {
                pB0 = ld_coh(g2_ws, gbase + (size_t)(2 * kgp + 6) * 64);
                pB1 = ld_coh(g2_ws, gbase + (size_t)(2 * kgp + 7) * 64);
            }
        }
        {   // kg = 2*kgp
            int kg = 2 * kgp;
            uint4 c0 = lphi[kg * 32 + lm];
            uint4 c1 = lphi[kg * 32 + 16 + lm];
            uint4 cg[4];
            #pragma unroll
            for (int ct = 0; ct < 4; ++ct)
                cg[ct] = lg2[buf + ct * 64 + lane];
            KG_STEP(c0, c1, cg);
        }
        {   // kg = 2*kgp + 1
            int kg = 2 * kgp + 1;
            uint4 c0 = lphi[kg * 32 + lm];
            uint4 c1 = lphi[kg * 32 + 16 + lm];
            uint4 cg[4];
            #pragma unroll
            for (int ct = 0; ct < 4; ++ct)
                cg[ct] = lg2[buf + 256 + ct * 64 + lane];
            KG_STEP(c0, c1, cg);
        }
        __syncthreads();
    }

    // softmax denominators: quads partition the 32 keys/kg at q=lm
    float inv[2];
    {
        float l0 = lsum[0]; l0 += __shfl_xor(l0, 16); l0 += __shfl_xor(l0, 32);
        float l1 = lsum[1]; l1 += __shfl_xor(l1, 16); l1 += __shfl_xor(l1, 32);
        inv[0] = 1.0f / l0; inv[1] = 1.0f / l1;
    }

    const float gamma = gamma_p[0];

    // transpose epilogue: normalized acc -> ltr[co][q'] (last loop barrier
    // already drained all lphi/lg2 reads), then coalesced stores
    #pragma unroll
    for (int qt = 0; qt < 2; ++qt)
        #pragma unroll
        for (int ct = 0; ct < 4; ++ct)
            #pragma unroll
            for (int r = 0; r < 4; ++r)
                ltr[(ct * 16 + quad * 4 + r) * 140 + w * 32 + qt * 16 + lm]
                    = acc[qt][ct][r] * inv[qt];
    __syncthreads();

    // 16-lane group covers one co row of 128 q; residual x from registers
    {
        const int l16 = t & 15;
        #pragma unroll
        for (int io = 0; io < 4; ++io) {
            int co = io * 16 + (t >> 4);
            size_t base = ((size_t)b * NC + co) * NN + (size_t)ph * 128 + l16 * 8;
            const float* tr = &ltr[co * 140 + l16 * 8];
            float4 t0 = ((const float4*)tr)[0];
            float4 t1 = ((const float4*)tr)[1];
            float4 o0 = make_float4(fmaf(gamma, t0.x, xr0[io].x), fmaf(gamma, t0.y, xr0[io].y),
                                    fmaf(gamma, t0.z, xr0[io].z), fmaf(gamma, t0.w, xr0[io].w));
            float4 o1 = make_float4(fmaf(gamma, t1.x, xr1[io].x), fmaf(gamma, t1.y, xr1[io].y),
                                    fmaf(gamma, t1.z, xr1[io].z), fmaf(gamma, t1.w, xr1[io].w));
            *(float4*)(out + base)     = o0;
            *(float4*)(out + base + 4) = o1;
        }
    }
}

// ---------------------------------------------------------------------------
extern "C" void kernel_launch(void* const* d_in, const int* in_sizes, int n_in,
                              void* d_out, int out_size, void* d_ws, size_t ws_size,
                              hipStream_t stream)
{
    const float* x  = (const float*)d_in[0];
    const float* wt = (const float*)d_in[1];
    const float* wp = (const float*)d_in[2];
    const float* wg = (const float*)d_in[3];
    const float* wo = (const float*)d_in[4];
    const float* gm = (const float*)d_in[5];
    float* out = (float*)d_out;

    // ws (bf16, packed): phi 256 KB | g2 (frag order) 2 MB | barrier flags
    unsigned* phi_ws = (unsigned*)d_ws;
    unsigned* g2_ws  = phi_ws + (size_t)NB * NM * ND / 2;
    int* flags = (int*)((char*)d_ws + (size_t)(256 * 1024 + 2 * 1024 * 1024));

    init_flags<<<1, NB * 32, 0, stream>>>(flags);
    fused_kernel<<<NB * 32, 256, 0, stream>>>(x, wt, wp, wg, wo, gm,
                                              phi_ws, g2_ws, flags, out);
}